// Round 5
// baseline (1275.737 us; speedup 1.0000x reference)
//
#include <hip/hip_runtime.h>

// Viterbi / CRF decode: B=32, S=512, T=128.
// R5: latency-optimized serial chain. 16 slices/batch, each slice = one block
// of 2 waves: wave0 computes its 8-row partial + publishes; wave1 spin-reads
// all 16 slice partials for its own 8 columns, merges, hands fs back via LDS.
// No s_barrier anywhere; vmcnt is per-wave so wave1's spin cannot drain
// wave0's 2-deep global prefetch.
// Packed key u64 = {flip(val):32 | s<<8 | (127-i)}: unsigned max == reference
// first-max (exact max value; ties -> smallest i). Tag (bits 8..23 == s) is
// self-validating; parity slots; stale replay tags carry bitwise-identical
// values (deterministic recurrence) so re-reads are harmless.

constexpr int S    = 512;
constexpr int T    = 128;
constexpr int NSL  = 16;         // slices (blocks) per batch
constexpr int ROWS = T / NSL;    // 8 rows per slice

using u64 = unsigned long long;
using u32 = unsigned int;

__device__ __forceinline__ u32 flipf(u32 u) {
    // monotone: float order -> unsigned order (no NaNs in inputs)
    return u ^ (0x80000000u | (u32)((int)u >> 31));
}
__device__ __forceinline__ u32 unflipf(u32 y) {
    return y ^ (0x80000000u | ~(u32)((int)y >> 31));
}

// ---------------- forward: grid = 32 batches x 16 slices, 128 thr ----------
__global__ __launch_bounds__(128, 1)
void viterbi_fwd(const float* __restrict__ c0, const float* __restrict__ c1,
                 const int* __restrict__ sofp,
                 u64* __restrict__ pub,           // [32][2][NSL][T]
                 unsigned char* __restrict__ bp)  // [32][S][T]
{
    __shared__ float fs_lds[ROWS];
    __shared__ int   seq_lds;

    const int g    = blockIdx.x;
    const int b    = g & 31;        // batch; g%8==b%8 -> slices share an XCD
    const int k    = g >> 5;        // slice 0..15
    const int tid  = (int)threadIdx.x;
    const int wv   = tid >> 6;
    const int l    = tid & 63;
    const int row0 = k * ROWS;

    const float* c0b = c0 + (size_t)b * (S + 1) * T * T;
    const float* c1b = c1 + (size_t)b * (S + 1) * T;
    u64* pubB = pub + (size_t)b * 2 * NSL * T;

    if (wv == 0) {
        // ---------------- wave0: compute + publish ----------------
        if (l == 0) seq_lds = 0;

        const int rA   = 2 * (l >> 4);      // local rows {rA, rA+1}
        const int cB   = (l & 15) * 8;      // 8 owned columns
        const u32 tieA = (u32)(127 - (row0 + rA));
        const u32 tieB = (u32)(127 - (row0 + rA + 1));

        const int sof = sofp[0];
        float f0 = c0b[(size_t)sof * T + row0 + rA]     * c1b[row0 + rA];
        float f1 = c0b[(size_t)sof * T + row0 + rA + 1] * c1b[row0 + rA + 1];

        const float* pA = c0b + (size_t)T * T + (size_t)(row0 + rA) * T + cB;
        const float* qA = c1b + T + cB;
        const float* pB = pA + T * T;
        const float* qB = qA + T;

        // set = 6 float4: rows rA (2), rA+1 (2), t1 (2)
        float4 A00 = *(const float4*)(pA);
        float4 A01 = *(const float4*)(pA + 4);
        float4 A10 = *(const float4*)(pA + T);
        float4 A11 = *(const float4*)(pA + T + 4);
        float4 At0 = *(const float4*)(qA);
        float4 At1 = *(const float4*)(qA + 4);
        float4 B00 = *(const float4*)(pB);
        float4 B01 = *(const float4*)(pB + 4);
        float4 B10 = *(const float4*)(pB + T);
        float4 B11 = *(const float4*)(pB + T + 4);
        float4 Bt0 = *(const float4*)(qB);
        float4 Bt1 = *(const float4*)(qB + 4);

        auto STEP = [&](int s, float4& x00, float4& x01, float4& x10,
                        float4& x11, float4& xt0, float4& xt1,
                        const float*& pp, const float*& qq) {
            const u32 sTag = (u32)s << 8;
            const u32 loA  = sTag | tieA;
            const u32 loB  = sTag | tieB;

            // exact ref order: (fs[i] + t1[j]) + t0[i,j]; ascending i with
            // strict > == packed-max with tie byte.
            auto mk = [&](float a0c, float a1c, float t1c) -> u64 {
                float vA = (f0 + t1c) + a0c;
                float vB = (f1 + t1c) + a1c;
                bool  t  = vB > vA;
                u32 hi = flipf(__float_as_uint(t ? vB : vA));
                u32 lo = t ? loB : loA;
                return ((u64)hi << 32) | lo;
            };
            u64 k0 = mk(x00.x, x10.x, xt0.x);
            u64 k1 = mk(x00.y, x10.y, xt0.y);
            u64 k2 = mk(x00.z, x10.z, xt0.z);
            u64 k3 = mk(x00.w, x10.w, xt0.w);
            u64 k4 = mk(x01.x, x11.x, xt1.x);
            u64 k5 = mk(x01.y, x11.y, xt1.y);
            u64 k6 = mk(x01.z, x11.z, xt1.z);
            u64 k7 = mk(x01.w, x11.w, xt1.w);

            // prefetch step s+2 into this now-dead set (wave0 never waits
            // vmcnt(0); compiler emits exact-count waits at next use).
            if (s + 2 <= S) {
                pp += 2 * T * T;
                qq += 2 * T;
                x00 = *(const float4*)(pp);
                x01 = *(const float4*)(pp + 4);
                x10 = *(const float4*)(pp + T);
                x11 = *(const float4*)(pp + T + 4);
                xt0 = *(const float4*)(qq);
                xt1 = *(const float4*)(qq + 4);
            }

            // butterfly over the 4 row-group lanes (l^16, l^32): u64 max.
            auto red = [&](u64& kk) {
                u64 p16 = __shfl_xor(kk, 16, 64); if (p16 > kk) kk = p16;
                u64 p32 = __shfl_xor(kk, 32, 64); if (p32 > kk) kk = p32;
            };
            red(k0); red(k1); red(k2); red(k3);
            red(k4); red(k5); red(k6); red(k7);

            // publish 2 of the 8 (all 4 redundant lane-groups cover all 8):
            // lane stores cols cB + rA, cB + rA + 1 (static select, no array).
            u64 ka = (rA == 0) ? k0 : (rA == 2) ? k2 : (rA == 4) ? k4 : k6;
            u64 kb = (rA == 0) ? k1 : (rA == 2) ? k3 : (rA == 4) ? k5 : k7;
            u64* ps = pubB + (size_t)(s & 1) * NSL * T + (size_t)k * T + cB + rA;
            __hip_atomic_store(ps,     ka, __ATOMIC_RELAXED, __HIP_MEMORY_SCOPE_AGENT);
            __hip_atomic_store(ps + 1, kb, __ATOMIC_RELAXED, __HIP_MEMORY_SCOPE_AGENT);

            // wait for wave1's merged fs(s) (LDS-only spin: lgkm, not vmcnt).
            while (__hip_atomic_load(&seq_lds, __ATOMIC_ACQUIRE,
                                     __HIP_MEMORY_SCOPE_WORKGROUP) != s) {}
            float2 fp = *(const float2*)&fs_lds[rA];
            f0 = fp.x;
            f1 = fp.y;
        };

        for (int s = 1; s <= S; s += 2) {
            STEP(s,     A00, A01, A10, A11, At0, At1, pA, qA);
            STEP(s + 1, B00, B01, B10, B11, Bt0, Bt1, pB, qB);
        }
    } else {
        // ---------------- wave1: exchange agent ----------------
        const int row = l & 7;                 // local row it collects
        const int slq = (l >> 3) * 2;          // slice pair
        const size_t joff = (size_t)(row0 + row);

        for (int s = 1; s <= S; ++s) {
            const u64* p0 = pubB + (size_t)(s & 1) * NSL * T +
                            (size_t)slq * T + joff;
            u64 v0, v1;
            for (;;) {
                v0 = __hip_atomic_load(p0,     __ATOMIC_RELAXED, __HIP_MEMORY_SCOPE_AGENT);
                v1 = __hip_atomic_load(p0 + T, __ATOMIC_RELAXED, __HIP_MEMORY_SCOPE_AGENT);
                bool ok = (((u32)v0 >> 8) == (u32)s) && (((u32)v1 >> 8) == (u32)s);
                if (__all(ok)) break;
            }
            u64 m = (v1 > v0) ? v1 : v0;   // keys are unique (tie byte)
            { u64 p = __shfl_xor(m, 8,  64); if (p > m) m = p; }
            { u64 p = __shfl_xor(m, 16, 64); if (p > m) m = p; }
            { u64 p = __shfl_xor(m, 32, 64); if (p > m) m = p; }
            // every lane now holds the final key for its row (l&7).
            if (l < 8) {
                float val = __uint_as_float(unflipf((u32)(m >> 32)));
                int   ii  = 127 - (int)((u32)m & 0xffu);
                fs_lds[l] = val;
                bp[((size_t)b * S + (s - 1)) * T + row0 + l] = (unsigned char)ii;
            }
            if (l == 0)
                __hip_atomic_store(&seq_lds, s, __ATOMIC_RELEASE,
                                   __HIP_MEMORY_SCOPE_WORKGROUP);
        }
    }
}

// ---------------- backtrack: one block per batch ---------------------------
__global__ __launch_bounds__(1024, 1)
void viterbi_bwd(const unsigned char* __restrict__ bp,
                 const int* __restrict__ eofp, int* __restrict__ out)
{
    __shared__ unsigned char lbp[S][T];  // 64 KB
    const int b   = blockIdx.x;
    const int tid = (int)threadIdx.x;

    const uint4* s4 = (const uint4*)(bp + (size_t)b * S * T);
    uint4* d4 = (uint4*)&lbp[0][0];
    #pragma unroll
    for (int it = 0; it < 4; ++it) d4[tid + it * 1024] = s4[tid + it * 1024];
    __syncthreads();

    if (tid == 0) {
        int ptr = lbp[S - 1][eofp[0]];
        for (int idx = S - 1; idx >= 0; --idx) {
            ptr = lbp[idx][ptr];
            out[(size_t)b * S + idx] = ptr;
        }
    }
}

// ---------------- fallback (proven R2 kernel) if ws too small --------------
__global__ __launch_bounds__(1024, 1)
void viterbi_fused_fb(const float* __restrict__ c0, const float* __restrict__ c1,
                      const int* __restrict__ sofp, const int* __restrict__ eofp,
                      int* __restrict__ out)
{
    __shared__ float fs[2][T];
    __shared__ float pmax[32][T];
    __shared__ int   parg[32][T];
    __shared__ unsigned char bpl[S][T];

    const int b   = blockIdx.x;
    const int tid = (int)threadIdx.x;
    const int jq  = tid & 31;
    const int g   = tid >> 5;
    const int col = jq * 4;
    const int row = g * 4;

    const float* c0b = c0 + (size_t)b * (S + 1) * T * T;
    const float* c1b = c1 + (size_t)b * (S + 1) * T;

    if (tid < T) {
        const int sof = sofp[0];
        fs[0][tid] = c0b[(size_t)sof * T + tid] * c1b[tid];
    }
    __syncthreads();

    const float* t0p = c0b + (size_t)T * T;
    float4 a0 = *(const float4*)(t0p + (size_t)(row + 0) * T + col);
    float4 a1 = *(const float4*)(t0p + (size_t)(row + 1) * T + col);
    float4 a2 = *(const float4*)(t0p + (size_t)(row + 2) * T + col);
    float4 a3 = *(const float4*)(t0p + (size_t)(row + 3) * T + col);
    float4 tv = *(const float4*)(c1b + T + col);

    int p = 0;
    for (int s = 1; s <= S; ++s) {
        float4 b0 = make_float4(0.f,0.f,0.f,0.f), b1 = b0, b2 = b0, b3 = b0, bt = b0;
        if (s < S) {
            const float* n0 = c0b + (size_t)(s + 1) * T * T;
            b0 = *(const float4*)(n0 + (size_t)(row + 0) * T + col);
            b1 = *(const float4*)(n0 + (size_t)(row + 1) * T + col);
            b2 = *(const float4*)(n0 + (size_t)(row + 2) * T + col);
            b3 = *(const float4*)(n0 + (size_t)(row + 3) * T + col);
            bt = *(const float4*)(c1b + (size_t)(s + 1) * T + col);
        }
        const float f0 = fs[p][row + 0];
        const float f1 = fs[p][row + 1];
        const float f2 = fs[p][row + 2];
        const float f3 = fs[p][row + 3];

        float bx, by, bz, bw; int ix, iy, iz, iw; float v;
        bx = (f0 + tv.x) + a0.x; ix = row;
        by = (f0 + tv.y) + a0.y; iy = row;
        bz = (f0 + tv.z) + a0.z; iz = row;
        bw = (f0 + tv.w) + a0.w; iw = row;
        v = (f1 + tv.x) + a1.x; if (v > bx) { bx = v; ix = row + 1; }
        v = (f1 + tv.y) + a1.y; if (v > by) { by = v; iy = row + 1; }
        v = (f1 + tv.z) + a1.z; if (v > bz) { bz = v; iz = row + 1; }
        v = (f1 + tv.w) + a1.w; if (v > bw) { bw = v; iw = row + 1; }
        v = (f2 + tv.x) + a2.x; if (v > bx) { bx = v; ix = row + 2; }
        v = (f2 + tv.y) + a2.y; if (v > by) { by = v; iy = row + 2; }
        v = (f2 + tv.z) + a2.z; if (v > bz) { bz = v; iz = row + 2; }
        v = (f2 + tv.w) + a2.w; if (v > bw) { bw = v; iw = row + 2; }
        v = (f3 + tv.x) + a3.x; if (v > bx) { bx = v; ix = row + 3; }
        v = (f3 + tv.y) + a3.y; if (v > by) { by = v; iy = row + 3; }
        v = (f3 + tv.z) + a3.z; if (v > bz) { bz = v; iz = row + 3; }
        v = (f3 + tv.w) + a3.w; if (v > bw) { bw = v; iw = row + 3; }

        *(float4*)&pmax[g][col] = make_float4(bx, by, bz, bw);
        *(int4*)  &parg[g][col] = make_int4(ix, iy, iz, iw);
        __syncthreads();

        if (tid < T) {
            float bb = pmax[0][tid];
            int   ii = parg[0][tid];
            #pragma unroll
            for (int gg = 1; gg < 32; ++gg) {
                float vv = pmax[gg][tid];
                if (vv > bb) { bb = vv; ii = parg[gg][tid]; }
            }
            fs[p ^ 1][tid] = bb;
            bpl[s - 1][tid] = (unsigned char)ii;
        }
        __syncthreads();
        p ^= 1;
        a0 = b0; a1 = b1; a2 = b2; a3 = b3; tv = bt;
    }

    if (tid == 0) {
        const int eof = eofp[0];
        int ptr = bpl[S - 1][eof];
        for (int idx = S - 1; idx >= 0; --idx) {
            ptr = bpl[idx][ptr];
            out[(size_t)b * S + idx] = ptr;
        }
    }
}

extern "C" void kernel_launch(void* const* d_in, const int* in_sizes, int n_in,
                              void* d_out, int out_size, void* d_ws, size_t ws_size,
                              hipStream_t stream)
{
    const float* c0  = (const float*)d_in[0];
    const float* c1  = (const float*)d_in[1];
    const int*   sof = (const int*)d_in[2];
    const int*   eof = (const int*)d_in[3];
    int*         out = (int*)d_out;

    const int B = in_sizes[1] / ((S + 1) * T);   // 32

    const size_t pub_bytes = (size_t)B * 2 * NSL * T * 8;   // 1 MB
    const size_t bp_bytes  = (size_t)B * S * T;             // 2 MB
    if (ws_size >= pub_bytes + bp_bytes) {
        u64* pub = (u64*)d_ws;
        unsigned char* bp = (unsigned char*)d_ws + pub_bytes;
        viterbi_fwd<<<dim3(B * NSL), dim3(128), 0, stream>>>(c0, c1, sof, pub, bp);
        viterbi_bwd<<<dim3(B), dim3(1024), 0, stream>>>(bp, eof, out);
    } else {
        viterbi_fused_fb<<<dim3(B), dim3(1024), 0, stream>>>(c0, c1, sof, eof, out);
    }
}

// Round 7
// 817.907 us; speedup vs baseline: 1.5598x; 1.5598x over previous
//
#include <hip/hip_runtime.h>

// Viterbi / CRF decode: B=32, S=512, T=128.
// R7 = R6 with the staging bug fixed: step-a slice source now includes the
// block's own row offset (k*RW*T). R6 staged rows 0..15 for every slice ->
// wrong phase-A inputs for k>0.
//
// Structure (R6): 2-step windows (max-plus associativity) -> ONE cross-CU
// exchange per 2 steps. 8 i-slice blocks per batch, 512 threads each.
// Window w (steps a=2w+1, b=2w+2):
//   phase A: block k computes ga_k[j] = max_{i in slice}(fs[i]+t1a[j])+t0a[i,j]
//            (quad-shfl merge), publishes pubG[k][j] = {flip(val),(127-i),tag}.
//   phase B: block k computes h_k[m] = max_j (ga_k[j]+t1b[m])+t0b[j,m] over ALL
//            128 j (t0b staged in LDS), publishes pubH[k][m].
//   poll:    256 threads each poll ONE u64 (pubH/pubG, all 8 slices, own 16
//            cols); merge: fs(next) + bp_b from pubH, bp_a from pubG.
// Correctness: fp-add monotone -> max over (k,j) == max over j bit-exact; any
// column reaching the max via a partial ga is a true argmax column, so the
// smallest-j tie byte preserves np.argmax first-max semantics. Keys:
// u64 {flip(val):32|(127-idx):8|tag:24} -> unsigned max == first-max; tag
// self-validates (parity slots; stale replay tags carry identical values).
// Scheduling: stager waves (tid>=256) own all global_load_lds; pollers' vmcnt
// holds only poll loads; staging overlaps the spin; stagers drain vmcnt(0)
// before the post-poll barrier. All barriers lgkmcnt-only.

constexpr int S   = 512;
constexpr int T   = 128;
constexpr int NSL = 8;        // slices (blocks) per batch
constexpr int RW  = 16;       // rows per slice
constexpr int NW  = S / 2;    // 256 windows

using u64 = unsigned long long;
using u32 = unsigned int;

__device__ __forceinline__ void bar_lds() {
    asm volatile("s_waitcnt lgkmcnt(0)" ::: "memory");
    __builtin_amdgcn_s_barrier();
}
__device__ __forceinline__ u32 flipf(u32 u)   { return u ^ (0x80000000u | (u32)((int)u >> 31)); }
__device__ __forceinline__ u32 unflipf(u32 y) { return y ^ (0x80000000u | ~(u32)((int)y >> 31)); }
__device__ __forceinline__ u64 aload(const u64* p) {
    return __hip_atomic_load(p, __ATOMIC_RELAXED, __HIP_MEMORY_SCOPE_AGENT);
}
__device__ __forceinline__ void astore(u64* p, u64 v) {
    __hip_atomic_store(p, v, __ATOMIC_RELAXED, __HIP_MEMORY_SCOPE_AGENT);
}

#define GLDS(srcp, dstp) \
    __builtin_amdgcn_global_load_lds( \
        (const __attribute__((address_space(1))) void*)(srcp), \
        (__attribute__((address_space(3))) void*)(dstp), 16, 0, 0)

__global__ __launch_bounds__(512, 1)
void viterbi_fwd2(const float* __restrict__ c0, const float* __restrict__ c1,
                  const int* __restrict__ sofp,
                  u64* __restrict__ pubG, u64* __restrict__ pubH,
                  unsigned char* __restrict__ bp)
{
    __shared__ float t0b_lds[2][T * T];        // 128 KB, double-buffered step-b tile
    __shared__ float t0a_lds[RW * T];          // 8 KB, single-buffered step-a slice
    __shared__ float part_v[16 * 130];         // phase-B partial values (padded)
    __shared__ unsigned char part_j[16 * 132]; // phase-B partial argmax-j (padded)
    __shared__ float gaval[T];
    __shared__ float fs_lds[RW];
    __shared__ u64   pollH[128];
    __shared__ u64   pollG[128];

    const int g    = blockIdx.x;
    const int b    = g & 31;          // batch; g%8==b%8 -> slices share an XCD
    const int k    = g >> 5;          // slice 0..7
    const int tid  = (int)threadIdx.x;
    const int wv   = tid >> 6;        // wave 0..7; waves 4..7 = stagers
    const int lane = tid & 63;

    const float* c0b = c0 + (size_t)b * (S + 1) * T * T;
    const float* c1b = c1 + (size_t)b * (S + 1) * T;
    u64* pG = pubG + (size_t)b * 2 * NSL * T;
    u64* pH = pubH + (size_t)b * 2 * NSL * T;

    const int jA  = tid >> 2;         // phase A: column 0..127
    const int ihA = tid & 3;          //          i-quad within slice
    const int jh  = tid >> 5;         // phase B: j-strip 0..15 (8 j's)
    const int mq  = tid & 31;         //          m-quad (4 m's)

    // Stager: stage window w's t0a slice (OWN rows: + k*RW*T  <-- R6 fix) and
    // t0b full tile. Linear LDS dest (wave-uniform base + lane*16B), per-lane
    // global source. Waves 4..7 only.
    auto STAGE = [&](int w) {
        if (wv < 4) return;
        const int fo = (wv - 4) * 256 + lane * 4;     // lane float offset
        const float* srcB = c0b + (size_t)(2 * w + 2) * T * T + fo;
        float* dstB = &t0b_lds[w & 1][(wv - 4) * 256];
        #pragma unroll
        for (int q = 0; q < 16; ++q)
            GLDS(srcB + q * 1024, dstB + q * 1024);
        const float* srcA = c0b + (size_t)(2 * w + 1) * T * T
                          + (size_t)k * RW * T + fo;          // own slice rows!
        float* dstA = &t0a_lds[(wv - 4) * 256];
        #pragma unroll
        for (int q = 0; q < 2; ++q)
            GLDS(srcA + q * 1024, dstA + q * 1024);
    };

    // ---- prologue: stage window 0, init fs, prefetch t1 regs ----
    STAGE(0);
    float  t1a_s = c1b[(size_t)1 * T + jA];
    float4 t1b_s = *(const float4*)&c1b[(size_t)2 * T + mq * 4];
    if (tid < RW) {
        const int sof = sofp[0];
        fs_lds[tid] = c0b[(size_t)sof * T + k * RW + tid] * c1b[k * RW + tid];
    }
    asm volatile("s_waitcnt vmcnt(0)" ::: "memory");
    bar_lds();

    for (int w = 0; w < NW; ++w) {
        const u32 tagw = (u32)(w + 1);

        // ---------------- phase A: own-slice step a ----------------
        {
            float bv; int bi;
            {
                float f = fs_lds[ihA * 4 + 0];
                bv = (f + t1a_s) + t0a_lds[(ihA * 4 + 0) * T + jA];
                bi = ihA * 4 + 0;
            }
            #pragma unroll
            for (int d = 1; d < 4; ++d) {
                float f = fs_lds[ihA * 4 + d];
                float v = (f + t1a_s) + t0a_lds[(ihA * 4 + d) * T + jA];
                if (v > bv) { bv = v; bi = ihA * 4 + d; }   // strict >: lowest i
            }
            u64 kk = ((u64)flipf(__float_as_uint(bv)) << 32)
                   | ((u32)(127 - (k * RW + bi)) << 24) | tagw;
            u64 p1 = __shfl_xor(kk, 1, 64); if (p1 > kk) kk = p1;
            u64 p2 = __shfl_xor(kk, 2, 64); if (p2 > kk) kk = p2;
            if (ihA == 0) {
                astore(&pG[(size_t)(w & 1) * NSL * T + (size_t)k * T + jA], kk);
                gaval[jA] = __uint_as_float(unflipf((u32)(kk >> 32)));
            }
        }
        bar_lds();

        // ---------------- phase B: full step b vs own ga ----------------
        {
            const float4 ga0 = *(const float4*)&gaval[jh * 8];
            const float4 ga1 = *(const float4*)&gaval[jh * 8 + 4];
            const float* tb = &t0b_lds[w & 1][0];
            float bv0, bv1, bv2, bv3; int bj0, bj1, bj2, bj3;
            {
                const int j = jh * 8;
                float4 t0 = *(const float4*)&tb[j * T + mq * 4];
                bv0 = (ga0.x + t1b_s.x) + t0.x;
                bv1 = (ga0.x + t1b_s.y) + t0.y;
                bv2 = (ga0.x + t1b_s.z) + t0.z;
                bv3 = (ga0.x + t1b_s.w) + t0.w;
                bj0 = bj1 = bj2 = bj3 = j;
            }
            const float gs[8] = {ga0.x, ga0.y, ga0.z, ga0.w, ga1.x, ga1.y, ga1.z, ga1.w};
            #pragma unroll
            for (int jj = 1; jj < 8; ++jj) {
                const int j = jh * 8 + jj;
                const float gg = gs[jj];
                float4 t0 = *(const float4*)&tb[j * T + mq * 4];
                float v;
                v = (gg + t1b_s.x) + t0.x; if (v > bv0) { bv0 = v; bj0 = j; }
                v = (gg + t1b_s.y) + t0.y; if (v > bv1) { bv1 = v; bj1 = j; }
                v = (gg + t1b_s.z) + t0.z; if (v > bv2) { bv2 = v; bj2 = j; }
                v = (gg + t1b_s.w) + t0.w; if (v > bv3) { bv3 = v; bj3 = j; }
            }
            *(float4*)&part_v[jh * 130 + mq * 4] = make_float4(bv0, bv1, bv2, bv3);
            *(u32*)&part_j[jh * 132 + mq * 4] =
                (u32)bj0 | ((u32)bj1 << 8) | ((u32)bj2 << 16) | ((u32)bj3 << 24);
        }
        bar_lds();

        // ---- mergeB + publish H (tid<128) ; staging + t1 prefetch ----
        if (tid < 128) {
            float bv = part_v[tid]; int bt = 0;
            #pragma unroll
            for (int t = 1; t < 16; ++t) {
                float v = part_v[t * 130 + tid];
                if (v > bv) { bv = v; bt = t; }   // ascending t = ascending j
            }
            u32 j = part_j[bt * 132 + tid];
            astore(&pH[(size_t)(w & 1) * NSL * T + (size_t)k * T + tid],
                   ((u64)flipf(__float_as_uint(bv)) << 32) | ((127u - j) << 24) | tagw);
        }
        if (w + 1 < NW) STAGE(w + 1);
        float  t1a_n = t1a_s;
        float4 t1b_n = t1b_s;
        if (w + 1 < NW) {
            t1a_n = c1b[(size_t)(2 * w + 3) * T + jA];
            t1b_n = *(const float4*)&c1b[(size_t)(2 * w + 4) * T + mq * 4];
        }

        // ---------------- poll (1 u64 per thread) ----------------
        if (tid < 128) {
            const u64* p = &pH[(size_t)(w & 1) * NSL * T + (size_t)(tid & 7) * T
                               + (k * RW + (tid >> 3))];
            u64 v;
            do { v = aload(p); } while ((u32)(v & 0xFFFFFFu) != tagw);
            pollH[tid] = v;
        } else if (tid < 256) {
            const int t2 = tid - 128;
            const u64* p = &pG[(size_t)(w & 1) * NSL * T + (size_t)(t2 & 7) * T
                               + (k * RW + (t2 >> 3))];
            u64 v;
            do { v = aload(p); } while ((u32)(v & 0xFFFFFFu) != tagw);
            pollG[t2] = v;
        } else {
            // stagers: guarantee window w+1 tiles resident before next barrier
            asm volatile("s_waitcnt vmcnt(0)" ::: "memory");
        }
        bar_lds();

        // ---------------- final merges ----------------
        if (tid < 16) {
            u64 mh = pollH[tid * 8];
            #pragma unroll
            for (int t = 1; t < 8; ++t) { u64 c = pollH[tid * 8 + t]; if (c > mh) mh = c; }
            fs_lds[tid] = __uint_as_float(unflipf((u32)(mh >> 32)));
            bp[((size_t)b * S + (2 * w + 1)) * T + (k * RW + tid)] =
                (unsigned char)(127u - (((u32)mh >> 24) & 0xFFu));
        } else if (tid < 32) {
            const int t2 = tid - 16;
            u64 mg = pollG[t2 * 8];
            #pragma unroll
            for (int t = 1; t < 8; ++t) { u64 c = pollG[t2 * 8 + t]; if (c > mg) mg = c; }
            bp[((size_t)b * S + (2 * w)) * T + (k * RW + t2)] =
                (unsigned char)(127u - (((u32)mg >> 24) & 0xFFu));
        }
        bar_lds();

        t1a_s = t1a_n;
        t1b_s = t1b_n;
    }
}

// ---------------- backtrack: one block per batch ---------------------------
__global__ __launch_bounds__(1024, 1)
void viterbi_bwd(const unsigned char* __restrict__ bp,
                 const int* __restrict__ eofp, int* __restrict__ out)
{
    __shared__ unsigned char lbp[S][T];  // 64 KB
    const int b   = blockIdx.x;
    const int tid = (int)threadIdx.x;

    const uint4* s4 = (const uint4*)(bp + (size_t)b * S * T);
    uint4* d4 = (uint4*)&lbp[0][0];
    #pragma unroll
    for (int it = 0; it < 4; ++it) d4[tid + it * 1024] = s4[tid + it * 1024];
    __syncthreads();

    if (tid == 0) {
        int ptr = lbp[S - 1][eofp[0]];
        for (int idx = S - 1; idx >= 0; --idx) {
            ptr = lbp[idx][ptr];
            out[(size_t)b * S + idx] = ptr;
        }
    }
}

// ---------------- fallback (proven R2 kernel) if ws too small --------------
__global__ __launch_bounds__(1024, 1)
void viterbi_fused_fb(const float* __restrict__ c0, const float* __restrict__ c1,
                      const int* __restrict__ sofp, const int* __restrict__ eofp,
                      int* __restrict__ out)
{
    __shared__ float fs[2][T];
    __shared__ float pmax[32][T];
    __shared__ int   parg[32][T];
    __shared__ unsigned char bpl[S][T];

    const int b   = blockIdx.x;
    const int tid = (int)threadIdx.x;
    const int jq  = tid & 31;
    const int gg2 = tid >> 5;
    const int col = jq * 4;
    const int row = gg2 * 4;

    const float* c0b = c0 + (size_t)b * (S + 1) * T * T;
    const float* c1b = c1 + (size_t)b * (S + 1) * T;

    if (tid < T) {
        const int sof = sofp[0];
        fs[0][tid] = c0b[(size_t)sof * T + tid] * c1b[tid];
    }
    __syncthreads();

    const float* t0p = c0b + (size_t)T * T;
    float4 a0 = *(const float4*)(t0p + (size_t)(row + 0) * T + col);
    float4 a1 = *(const float4*)(t0p + (size_t)(row + 1) * T + col);
    float4 a2 = *(const float4*)(t0p + (size_t)(row + 2) * T + col);
    float4 a3 = *(const float4*)(t0p + (size_t)(row + 3) * T + col);
    float4 tv = *(const float4*)(c1b + T + col);

    int p = 0;
    for (int s = 1; s <= S; ++s) {
        float4 b0 = make_float4(0.f,0.f,0.f,0.f), b1 = b0, b2 = b0, b3 = b0, bt = b0;
        if (s < S) {
            const float* n0 = c0b + (size_t)(s + 1) * T * T;
            b0 = *(const float4*)(n0 + (size_t)(row + 0) * T + col);
            b1 = *(const float4*)(n0 + (size_t)(row + 1) * T + col);
            b2 = *(const float4*)(n0 + (size_t)(row + 2) * T + col);
            b3 = *(const float4*)(n0 + (size_t)(row + 3) * T + col);
            bt = *(const float4*)(c1b + (size_t)(s + 1) * T + col);
        }
        const float f0 = fs[p][row + 0];
        const float f1 = fs[p][row + 1];
        const float f2 = fs[p][row + 2];
        const float f3 = fs[p][row + 3];

        float bx, by, bz, bw; int ix, iy, iz, iw; float v;
        bx = (f0 + tv.x) + a0.x; ix = row;
        by = (f0 + tv.y) + a0.y; iy = row;
        bz = (f0 + tv.z) + a0.z; iz = row;
        bw = (f0 + tv.w) + a0.w; iw = row;
        v = (f1 + tv.x) + a1.x; if (v > bx) { bx = v; ix = row + 1; }
        v = (f1 + tv.y) + a1.y; if (v > by) { by = v; iy = row + 1; }
        v = (f1 + tv.z) + a1.z; if (v > bz) { bz = v; iz = row + 1; }
        v = (f1 + tv.w) + a1.w; if (v > bw) { bw = v; iw = row + 1; }
        v = (f2 + tv.x) + a2.x; if (v > bx) { bx = v; ix = row + 2; }
        v = (f2 + tv.y) + a2.y; if (v > by) { by = v; iy = row + 2; }
        v = (f2 + tv.z) + a2.z; if (v > bz) { bz = v; iz = row + 2; }
        v = (f2 + tv.w) + a2.w; if (v > bw) { bw = v; iw = row + 2; }
        v = (f3 + tv.x) + a3.x; if (v > bx) { bx = v; ix = row + 3; }
        v = (f3 + tv.y) + a3.y; if (v > by) { by = v; iy = row + 3; }
        v = (f3 + tv.z) + a3.z; if (v > bz) { bz = v; iz = row + 3; }
        v = (f3 + tv.w) + a3.w; if (v > bw) { bw = v; iw = row + 3; }

        *(float4*)&pmax[gg2][col] = make_float4(bx, by, bz, bw);
        *(int4*)  &parg[gg2][col] = make_int4(ix, iy, iz, iw);
        __syncthreads();

        if (tid < T) {
            float bb = pmax[0][tid];
            int   ii = parg[0][tid];
            #pragma unroll
            for (int q = 1; q < 32; ++q) {
                float vv = pmax[q][tid];
                if (vv > bb) { bb = vv; ii = parg[q][tid]; }
            }
            fs[p ^ 1][tid] = bb;
            bpl[s - 1][tid] = (unsigned char)ii;
        }
        __syncthreads();
        p ^= 1;
        a0 = b0; a1 = b1; a2 = b2; a3 = b3; tv = bt;
    }

    if (tid == 0) {
        const int eof = eofp[0];
        int ptr = bpl[S - 1][eof];
        for (int idx = S - 1; idx >= 0; --idx) {
            ptr = bpl[idx][ptr];
            out[(size_t)b * S + idx] = ptr;
        }
    }
}

extern "C" void kernel_launch(void* const* d_in, const int* in_sizes, int n_in,
                              void* d_out, int out_size, void* d_ws, size_t ws_size,
                              hipStream_t stream)
{
    const float* c0  = (const float*)d_in[0];
    const float* c1  = (const float*)d_in[1];
    const int*   sof = (const int*)d_in[2];
    const int*   eof = (const int*)d_in[3];
    int*         out = (int*)d_out;

    const int B = in_sizes[1] / ((S + 1) * T);   // 32

    const size_t pub_b = (size_t)B * 2 * NSL * T * 8;   // 512 KB each
    const size_t bp_b  = (size_t)B * S * T;             // 2 MB
    if (B == 32 && ws_size >= 2 * pub_b + bp_b) {
        u64* pubG = (u64*)d_ws;
        u64* pubH = (u64*)((char*)d_ws + pub_b);
        unsigned char* bp = (unsigned char*)d_ws + 2 * pub_b;
        viterbi_fwd2<<<dim3(B * NSL), dim3(512), 0, stream>>>(c0, c1, sof, pubG, pubH, bp);
        viterbi_bwd<<<dim3(B), dim3(1024), 0, stream>>>(bp, eof, out);
    } else {
        viterbi_fused_fb<<<dim3(B), dim3(1024), 0, stream>>>(c0, c1, sof, eof, out);
    }
}